// Round 5
// baseline (110.942 us; speedup 1.0000x reference)
//
#include <hip/hip_runtime.h>
#include <math.h>

#define B_N 4096
#define M_N 256
#define D_N 256
#define ROWS 4                      // rows per k_main block (R4's ROWS=2 reverted: +15% work > stall gain)
#define GRID_MAIN (B_N / ROWS)
#define NSLOT 64                    // partial-sum slots (1 per 64B line)
#define BLK_PER_SLOT (GRID_MAIN / NSLOT)
#define SCR_OFF 131072              // float offset of per-block ewp scratch (512KB in; wT ends at 73728)

constexpr float TAU_   = 0.2f;
constexpr float LAM_   = 8.0f;
constexpr float TOPO_  = 0.5f;
constexpr float LEN_C_ = 0.01f;
constexpr float SP_C_  = 0.001f;
constexpr float LOG2E_ = 1.44269504088896340736f;
constexpr float KSC    = LOG2E_ / TAU_;
constexpr float KL     = LOG2E_ / LAM_;
constexpr float C0_    = 133.0f;    // fixed exponent center: dist ~18.5 -> sc ~133

// ws float layout:
// [4]          cnt2 (uint, single)
// [16..272)    degree[256]
// [512..768)   wnorm[256]
// [1024..1280) pPart[256]
// [1280..1536) wpdPart[256]
// [2048..3072) S_slot[64] strided 16 floats (64B line each)
// [4096..5120) cnt1[64]  (uint) strided 16
// [8192..73728) wT[256*256]  (D x M transpose, fp32)
// [SCR_OFF..SCR_OFF+GRID_MAIN*1024) per-block ewp scratch (4KB/block, L2-resident)

__device__ __forceinline__ float wave_reduce_sum(float v) {
#pragma unroll
  for (int off = 1; off < 64; off <<= 1) v += __shfl_xor(v, off, 64);
  return v;
}

// Quad-combine: sum of 4 sigmoids with ONE rcp (R1; kept).
__device__ __forceinline__ void rank_quad(float iv, float iv2, float4 q,
                                          float& s) {
  float ta = fmaf(q.x, iv, 1.0f);     // 1 + es_a*iv
  float da = fmaf(q.y, iv2, ta);      // D2a
  float na = ta + 1.0f;               // N2a
  float tb = fmaf(q.z, iv, 1.0f);
  float db = fmaf(q.w, iv2, tb);      // D2b
  float nb = tb + 1.0f;               // N2b
  float d4 = da * db;
  float n4 = fmaf(na, db, nb * da);
  s = fmaf(n4, __builtin_amdgcn_rcpf(d4), s);
}

// Dispatch 1 (R2 version): blocks 0..255 transpose w -> wT + wnorm +
// zero accumulators; blocks 256..511 edge stats (reassociated, coalesced).
__global__ __launch_bounds__(256) void k_prep(const float* __restrict__ w,
                                              const float* __restrict__ E,
                                              float* __restrict__ ws) {
  int tid = threadIdx.x;
  if (blockIdx.x < M_N) {
    float* wT = ws + 8192;
    int j = blockIdx.x, d = tid;
    float v = w[j * D_N + d];
    wT[d * M_N + j] = v;
    float s = wave_reduce_sum(v * v);
    __shared__ float red[4];
    if ((d & 63) == 0) red[d >> 6] = s;
    if (j == 0) {
      if (d < 16) ws[d] = 0.0f;                       // cnt2 etc.
      if (d < NSLOT) {
        ws[2048 + 16 * d] = 0.0f;                     // S_slot
        ((unsigned*)ws)[4096 + 16 * d] = 0u;          // cnt1
      }
    }
    __syncthreads();
    if (d == 0) ws[512 + j] = red[0] + red[1] + red[2] + red[3];
  } else {
    int j = blockIdx.x - M_N;
    int k = tid;
    __shared__ __align__(16) float sp[M_N];   // p_k for this j
    __shared__ float redp[4], redt[4];

    float l = 0.5f * (E[j * M_N + k] + E[k * M_N + j]);
    float p = __builtin_amdgcn_rcpf(1.0f + __builtin_amdgcn_exp2f(-l * LOG2E_));
    if (k == j) p = 0.0f;
    sp[k] = p;

    float spw = wave_reduce_sum(p);
    if ((k & 63) == 0) redp[k >> 6] = spw;
    __syncthreads();
    float tp = redp[0] + redp[1] + redp[2] + redp[3];   // P (all threads)

    float A = 0.0f, Bv = 0.0f;
    const float4* sp4 = (const float4*)sp;
    const float* wb = w + tid;
#pragma unroll 4
    for (int k0 = 0; k0 < M_N / 4; k0++) {
      float4 pq = sp4[k0];
      const float* wr = wb + (size_t)(4 * k0) * D_N;
      float w0 = wr[0], w1 = wr[D_N], w2 = wr[2 * D_N], w3 = wr[3 * D_N];
      A  = fmaf(pq.x, w0 * w0, A); Bv = fmaf(pq.x, w0, Bv);
      A  = fmaf(pq.y, w1 * w1, A); Bv = fmaf(pq.y, w1, Bv);
      A  = fmaf(pq.z, w2 * w2, A); Bv = fmaf(pq.z, w2, Bv);
      A  = fmaf(pq.w, w3 * w3, A); Bv = fmaf(pq.w, w3, Bv);
    }

    float wj = w[j * D_N + tid];
    float v  = fmaf(tp, wj * wj, fmaf(-2.0f * wj, Bv, A));
    float sv = wave_reduce_sum(v);
    if ((k & 63) == 0) redt[k >> 6] = sv;
    __syncthreads();
    if (k == 0) {
      float tw = redt[0] + redt[1] + redt[2] + redt[3];
      ws[16 + j]   = tp * (1.0f / (float)(M_N - 1));
      ws[1024 + j] = tp;
      ws[1280 + j] = tw;
    }
  }
}

// Dispatch 2: fused fp32 GEMM + soft-rank (ROWS=4, R2 structure).
// R5 change: the rank-phase k-stream (ewp quads) moves from LDS broadcast
// reads to per-block GLOBAL scratch read via uniform VMEM loads.
// Rationale: the ds_read_b128 broadcast stream was the one invariant across
// R0/R1/R4 (all ~41.5us); VMEM path is idle (HBM 1%, L2-resident 4KB/block).
__global__ __launch_bounds__(256, 4) void k_main(const float* __restrict__ data,
                                                 float* __restrict__ ws,
                                                 float* __restrict__ out) {
  const float* wT     = ws + 8192;
  const float* wnorm  = ws + 512;
  const float* degree = ws + 16;
  float* S_slot  = ws + 2048;                 // stride 16 floats
  unsigned* cnt1 = (unsigned*)ws + 4096;      // stride 16
  unsigned* cnt2 = (unsigned*)ws + 4;
  float* ewg = ws + SCR_OFF + (size_t)blockIdx.x * (ROWS * M_N);

  __shared__ __align__(16) float ew[ROWS][M_N];   // e-values per row
  __shared__ float rednrm[ROWS][4];
  __shared__ float snrm[ROWS];
  __shared__ float redf[4], redp[4], redw[4];
  __shared__ int isLast;

  const int tid  = threadIdx.x;
  const int wv_  = tid >> 6;
  const int lane = tid & 63;
  const int b0   = blockIdx.x * ROWS;

  // row norms
#pragma unroll
  for (int r = 0; r < ROWS; r++) {
    float x = data[(size_t)(b0 + r) * D_N + tid];
    float s = wave_reduce_sum(x * x);
    if (lane == 0) rednrm[r][wv_] = s;
  }
  __syncthreads();
  if (tid < ROWS)
    snrm[tid] = rednrm[tid][0] + rednrm[tid][1] + rednrm[tid][2] + rednrm[tid][3];

  // GEMM: x rows block-uniform; wT coalesced per thread.
  // Register double-buffer: batch g+1's 16 loads issued before batch g is
  // consumed -> 16+ loads in flight at consumption.
  const float4* x0 = (const float4*)(data + (size_t)(b0 + 0) * D_N);
  const float4* x1 = (const float4*)(data + (size_t)(b0 + 1) * D_N);
  const float4* x2 = (const float4*)(data + (size_t)(b0 + 2) * D_N);
  const float4* x3 = (const float4*)(data + (size_t)(b0 + 3) * D_N);
  const float* pw = wT + tid;

  float a0 = 0.f, a1 = 0.f, a2 = 0.f, a3 = 0.f;
  float wreg[2][16];
#pragma unroll
  for (int i = 0; i < 16; i++) wreg[0][i] = pw[(size_t)i * M_N];

#pragma unroll
  for (int g = 0; g < 16; g++) {
    const int cur = g & 1, nxt = cur ^ 1;
    if (g < 15) {
#pragma unroll
      for (int i = 0; i < 16; i++)
        wreg[nxt][i] = pw[(size_t)((g + 1) * 16 + i) * M_N];
    }
#pragma unroll
    for (int i4 = 0; i4 < 4; i4++) {
      int d4 = 4 * g + i4;
      float4 xa = x0[d4], xb = x1[d4], xc = x2[d4], xd = x3[d4];
      float w0 = wreg[cur][4 * i4 + 0], w1 = wreg[cur][4 * i4 + 1];
      float w2 = wreg[cur][4 * i4 + 2], w3 = wreg[cur][4 * i4 + 3];
      a0 = fmaf(xa.x, w0, a0); a0 = fmaf(xa.y, w1, a0);
      a0 = fmaf(xa.z, w2, a0); a0 = fmaf(xa.w, w3, a0);
      a1 = fmaf(xb.x, w0, a1); a1 = fmaf(xb.y, w1, a1);
      a1 = fmaf(xb.z, w2, a1); a1 = fmaf(xb.w, w3, a1);
      a2 = fmaf(xc.x, w0, a2); a2 = fmaf(xc.y, w1, a2);
      a2 = fmaf(xc.z, w2, a2); a2 = fmaf(xc.w, w3, a2);
      a3 = fmaf(xd.x, w0, a3); a3 = fmaf(xd.y, w1, a3);
      a3 = fmaf(xd.z, w2, a3); a3 = fmaf(xd.w, w3, a3);
    }
  }
  __syncthreads();   // snrm visible

  // distances + e-values (dist stays in registers for j = tid)
  float wn = wnorm[tid];
  float acc[ROWS] = {a0, a1, a2, a3};
  float dist[ROWS], iv[ROWS], iv2[ROWS];
#pragma unroll
  for (int r = 0; r < ROWS; r++) {
    float sq = snrm[r] - 2.0f * acc[r] + wn;
    dist[r] = sqrtf(fmaxf(sq, 0.0f));
    float sc = dist[r] * KSC;
    ew[r][tid] = __builtin_amdgcn_exp2f(sc - C0_);
    iv[r]      = __builtin_amdgcn_exp2f(C0_ - sc);
    iv2[r]     = iv[r] * iv[r];
  }
  __syncthreads();

  // hoisted pair terms -> GLOBAL scratch (coalesced dwordx4 per thread):
  // thread (wave r, lane q) packs ew[r][4q..4q+3] into (es_a,ep_a,es_b,ep_b)
  {
    int r = tid >> 6, q = tid & 63;
    float4 e = *(const float4*)&ew[r][4 * q];
    float4 o = {e.x + e.y, e.x * e.y, e.z + e.w, e.z * e.w};
    *(float4*)&ewg[r * M_N + 4 * q] = o;
  }
  __syncthreads();   // block-level fence: global writes visible to block reads

  // rank: per row, sum_k sigmoid((d_j-d_k)/tau), quad-combined.
  // k-stream via uniform VMEM loads (L1/L2-hit broadcast), LDS pipe idle.
  float fj = 1.0f + TOPO_ * degree[tid];
  float tl = 0.0f;
#pragma unroll
  for (int r = 0; r < ROWS; r++) {
    float s = 0.0f;
    const float4* q4 = (const float4*)(ewg + r * M_N);
    float ivr = iv[r], iv2r = iv2[r];
#pragma unroll 16
    for (int k4 = 0; k4 < M_N / 4; k4++) {
      float4 q = q4[k4];                       // (es_a, ep_a, es_b, ep_b)
      rank_quad(ivr, iv2r, q, s);
    }
    // diagonal contributes exactly 0.5; soft_rank-1 = s-0.5
    float nb = __builtin_amdgcn_exp2f((0.5f - s) * KL);
    tl = fmaf(nb * dist[r], fj, tl);
  }

  float bs = wave_reduce_sum(tl);
  if (lane == 0) redf[wv_] = bs;
  __syncthreads();
  if (tid == 0) {
    float tot = redf[0] + redf[1] + redf[2] + redf[3];
    int slot = (int)(blockIdx.x & (NSLOT - 1));
    float old = atomicAdd(&S_slot[16 * slot], tot);
    asm volatile("" : "+v"(old));   // consume: slot-add committed before cnt1
    int last = 0;
    unsigned t1 = atomicAdd(&cnt1[16 * slot], 1u);
    if (t1 == (unsigned)(BLK_PER_SLOT - 1)) {        // slot closed
      unsigned t2 = atomicAdd(cnt2, 1u);             // only 64 ever reach here
      last = (t2 == (unsigned)(NSLOT - 1)) ? 1 : 0;  // all slots closed
    }
    isLast = last;
  }
  __syncthreads();

  if (isLast) {
    float p  = ws[1024 + tid];
    float wd = ws[1280 + tid];
    float rp = wave_reduce_sum(p);
    float rw = wave_reduce_sum(wd);
    if (lane == 0) { redp[wv_] = rp; redw[wv_] = rw; }
    float sd = 0.0f;
    if (wv_ == 0) {
      float v = atomicAdd(&S_slot[16 * lane], 0.0f);  // coherent slot read
      sd = wave_reduce_sum(v);
    }
    __syncthreads();
    if (tid == 0) {
      float Sp   = redp[0] + redp[1] + redp[2] + redp[3];
      float Swpd = redw[0] + redw[1] + redw[2] + redw[3];
      float data_term = sd * (1.0f / ((float)B_N * (float)M_N));
      float wl = Swpd / (Sp + 1e-8f);
      float sparsity = Sp * (1.0f / ((float)M_N * (float)M_N));
      out[0] = data_term + LEN_C_ * wl + SP_C_ * sparsity;
    }
  }
}

extern "C" void kernel_launch(void* const* d_in, const int* in_sizes, int n_in,
                              void* d_out, int out_size, void* d_ws, size_t ws_size,
                              hipStream_t stream) {
  const float* data = (const float*)d_in[0];
  const float* w    = (const float*)d_in[1];
  const float* E    = (const float*)d_in[2];
  float* ws = (float*)d_ws;

  k_prep<<<2 * M_N, 256, 0, stream>>>(w, E, ws);
  k_main<<<GRID_MAIN, 256, 0, stream>>>(data, ws, (float*)d_out);
}

// Round 6
// 107.178 us; speedup vs baseline: 1.0351x; 1.0351x over previous
//
#include <hip/hip_runtime.h>
#include <math.h>

#define B_N 4096
#define M_N 256
#define D_N 256
#define ROWS 8                      // R6: 4->8 — halves per-thread fixed cost + wT L2 stream
#define GRID_MAIN (B_N / ROWS)      // 512
#define NSLOT 64                    // partial-sum slots (1 per 64B line)
#define BLK_PER_SLOT (GRID_MAIN / NSLOT)

constexpr float TAU_   = 0.2f;
constexpr float LAM_   = 8.0f;
constexpr float TOPO_  = 0.5f;
constexpr float LEN_C_ = 0.01f;
constexpr float SP_C_  = 0.001f;
constexpr float LOG2E_ = 1.44269504088896340736f;
constexpr float KSC    = LOG2E_ / TAU_;
constexpr float KL     = LOG2E_ / LAM_;
constexpr float C0_    = 133.0f;    // fixed exponent center: dist ~18.5 -> sc ~133

// ws float layout (R2 layout):
// [4]          cnt2 (uint, single)
// [16..272)    degree[256]
// [512..768)   wnorm[256]
// [1024..1280) pPart[256]
// [1280..1536) wpdPart[256]
// [2048..3072) S_slot[64] strided 16 floats (64B line each)
// [4096..5120) cnt1[64]  (uint) strided 16
// [8192..73728) wT[256*256]  (D x M transpose, fp32)

__device__ __forceinline__ float wave_reduce_sum(float v) {
#pragma unroll
  for (int off = 1; off < 64; off <<= 1) v += __shfl_xor(v, off, 64);
  return v;
}

// Quad-combine: sum of 4 sigmoids with ONE rcp (R1; kept).
__device__ __forceinline__ void rank_quad(float iv, float iv2, float4 q,
                                          float& s) {
  float ta = fmaf(q.x, iv, 1.0f);     // 1 + es_a*iv
  float da = fmaf(q.y, iv2, ta);      // D2a
  float na = ta + 1.0f;               // N2a
  float tb = fmaf(q.z, iv, 1.0f);
  float db = fmaf(q.w, iv2, tb);      // D2b
  float nb = tb + 1.0f;               // N2b
  float d4 = da * db;
  float n4 = fmaf(na, db, nb * da);
  s = fmaf(n4, __builtin_amdgcn_rcpf(d4), s);
}

// Dispatch 1 (R2 version, proven): blocks 0..255 transpose w -> wT + wnorm +
// zero accumulators; blocks 256..511 edge stats (reassociated, coalesced).
__global__ __launch_bounds__(256) void k_prep(const float* __restrict__ w,
                                              const float* __restrict__ E,
                                              float* __restrict__ ws) {
  int tid = threadIdx.x;
  if (blockIdx.x < M_N) {
    float* wT = ws + 8192;
    int j = blockIdx.x, d = tid;
    float v = w[j * D_N + d];
    wT[d * M_N + j] = v;
    float s = wave_reduce_sum(v * v);
    __shared__ float red[4];
    if ((d & 63) == 0) red[d >> 6] = s;
    if (j == 0) {
      if (d < 16) ws[d] = 0.0f;                       // cnt2 etc.
      if (d < NSLOT) {
        ws[2048 + 16 * d] = 0.0f;                     // S_slot
        ((unsigned*)ws)[4096 + 16 * d] = 0u;          // cnt1
      }
    }
    __syncthreads();
    if (d == 0) ws[512 + j] = red[0] + red[1] + red[2] + red[3];
  } else {
    int j = blockIdx.x - M_N;
    int k = tid;
    __shared__ __align__(16) float sp[M_N];   // p_k for this j
    __shared__ float redp[4], redt[4];

    float l = 0.5f * (E[j * M_N + k] + E[k * M_N + j]);
    float p = __builtin_amdgcn_rcpf(1.0f + __builtin_amdgcn_exp2f(-l * LOG2E_));
    if (k == j) p = 0.0f;
    sp[k] = p;

    float spw = wave_reduce_sum(p);
    if ((k & 63) == 0) redp[k >> 6] = spw;
    __syncthreads();
    float tp = redp[0] + redp[1] + redp[2] + redp[3];   // P (all threads)

    float A = 0.0f, Bv = 0.0f;
    const float4* sp4 = (const float4*)sp;
    const float* wb = w + tid;
#pragma unroll 4
    for (int k0 = 0; k0 < M_N / 4; k0++) {
      float4 pq = sp4[k0];
      const float* wr = wb + (size_t)(4 * k0) * D_N;
      float w0 = wr[0], w1 = wr[D_N], w2 = wr[2 * D_N], w3 = wr[3 * D_N];
      A  = fmaf(pq.x, w0 * w0, A); Bv = fmaf(pq.x, w0, Bv);
      A  = fmaf(pq.y, w1 * w1, A); Bv = fmaf(pq.y, w1, Bv);
      A  = fmaf(pq.z, w2 * w2, A); Bv = fmaf(pq.z, w2, Bv);
      A  = fmaf(pq.w, w3 * w3, A); Bv = fmaf(pq.w, w3, Bv);
    }

    float wj = w[j * D_N + tid];
    float v  = fmaf(tp, wj * wj, fmaf(-2.0f * wj, Bv, A));
    float sv = wave_reduce_sum(v);
    if ((k & 63) == 0) redt[k >> 6] = sv;
    __syncthreads();
    if (k == 0) {
      float tw = redt[0] + redt[1] + redt[2] + redt[3];
      ws[16 + j]   = tp * (1.0f / (float)(M_N - 1));
      ws[1024 + j] = tp;
      ws[1280 + j] = tw;
    }
  }
}

// Dispatch 2: fused fp32 GEMM + soft-rank. R5's global-scratch rank stream
// REVERTED to LDS (WRITE_SIZE 68KB->4.2MB proved scratch went to HBM).
// R6: ROWS=8 (amortize per-thread fixed costs; wT L2 stream 256->128MB),
// wave-owned-row norms (barrier removed), shfl-built ewp (ew[] removed).
__global__ __launch_bounds__(256, 4) void k_main(const float* __restrict__ data,
                                                 float* __restrict__ ws,
                                                 float* __restrict__ out) {
  const float* wT     = ws + 8192;
  const float* wnorm  = ws + 512;
  const float* degree = ws + 16;
  float* S_slot  = ws + 2048;                 // stride 16 floats
  unsigned* cnt1 = (unsigned*)ws + 4096;      // stride 16
  unsigned* cnt2 = (unsigned*)ws + 4;

  __shared__ __align__(16) float ewp[ROWS][M_N];  // pairs: [2p]=es, [2p+1]=ep
  __shared__ float snrm[ROWS];
  __shared__ float redf[4], redp[4], redw[4];
  __shared__ int isLast;

  const int tid  = threadIdx.x;
  const int wv_  = tid >> 6;
  const int lane = tid & 63;
  const int b0   = blockIdx.x * ROWS;

  // row norms: wave v owns rows v and v+4; one float4 per lane (64*16B = row)
#pragma unroll
  for (int h = 0; h < 2; h++) {
    int r = wv_ + 4 * h;
    float4 xv = ((const float4*)(data + (size_t)(b0 + r) * D_N))[lane];
    float s = wave_reduce_sum(fmaf(xv.x, xv.x, fmaf(xv.y, xv.y,
                              fmaf(xv.z, xv.z, xv.w * xv.w))));
    if (lane == 0) snrm[r] = s;
  }
  // (snrm consumed after the GEMM barrier below — no extra barrier needed)

  // GEMM: x rows block-uniform; wT coalesced per thread.
  // Register double-buffer: batch g+1's 16 loads issued before batch g is
  // consumed -> 16+ loads in flight at consumption.
  const float4* xp[ROWS];
#pragma unroll
  for (int r = 0; r < ROWS; r++)
    xp[r] = (const float4*)(data + (size_t)(b0 + r) * D_N);
  const float* pw = wT + tid;

  float acc[ROWS];
#pragma unroll
  for (int r = 0; r < ROWS; r++) acc[r] = 0.0f;
  float wreg[2][16];
#pragma unroll
  for (int i = 0; i < 16; i++) wreg[0][i] = pw[(size_t)i * M_N];

#pragma unroll
  for (int g = 0; g < 16; g++) {
    const int cur = g & 1, nxt = cur ^ 1;
    if (g < 15) {
#pragma unroll
      for (int i = 0; i < 16; i++)
        wreg[nxt][i] = pw[(size_t)((g + 1) * 16 + i) * M_N];
    }
#pragma unroll
    for (int i4 = 0; i4 < 4; i4++) {
      int d4 = 4 * g + i4;
      float w0 = wreg[cur][4 * i4 + 0], w1 = wreg[cur][4 * i4 + 1];
      float w2 = wreg[cur][4 * i4 + 2], w3 = wreg[cur][4 * i4 + 3];
#pragma unroll
      for (int r = 0; r < ROWS; r++) {
        float4 xa = xp[r][d4];
        acc[r] = fmaf(xa.x, w0, acc[r]); acc[r] = fmaf(xa.y, w1, acc[r]);
        acc[r] = fmaf(xa.z, w2, acc[r]); acc[r] = fmaf(xa.w, w3, acc[r]);
      }
    }
  }
  __syncthreads();   // snrm visible; GEMM regs done

  // distances + e-values; ewp pairs built in-register via partner shuffle
  float wn = wnorm[tid];
  float dist[ROWS], iv[ROWS], iv2[ROWS];
#pragma unroll
  for (int r = 0; r < ROWS; r++) {
    float sq = snrm[r] - 2.0f * acc[r] + wn;
    dist[r] = sqrtf(fmaxf(sq, 0.0f));
    float sc = dist[r] * KSC;
    float ev = __builtin_amdgcn_exp2f(sc - C0_);
    iv[r]    = __builtin_amdgcn_exp2f(C0_ - sc);
    iv2[r]   = iv[r] * iv[r];
    float en = __shfl_xor(ev, 1, 64);          // partner j = tid^1
    if ((tid & 1) == 0) {                      // even lane owns pair idx tid/2
      float2 o = {ev + en, ev * en};
      *(float2*)&ewp[r][tid] = o;              // elements [tid], [tid+1]
    }
  }
  __syncthreads();

  // rank: per row, sum_k sigmoid((d_j-d_k)/tau), quad-combined (1 rcp / 4k)
  float fj = 1.0f + TOPO_ * degree[tid];
  float tl = 0.0f;
#pragma unroll
  for (int r = 0; r < ROWS; r++) {
    float s = 0.0f;
    const float4* q4 = (const float4*)(&ewp[r][0]);
    float ivr = iv[r], iv2r = iv2[r];
#pragma unroll 8
    for (int k4 = 0; k4 < M_N / 4; k4++) {
      float4 q = q4[k4];                       // (es_a, ep_a, es_b, ep_b)
      rank_quad(ivr, iv2r, q, s);
    }
    // diagonal contributes exactly 0.5; soft_rank-1 = s-0.5
    float nb = __builtin_amdgcn_exp2f((0.5f - s) * KL);
    tl = fmaf(nb * dist[r], fj, tl);
  }

  float bs = wave_reduce_sum(tl);
  if (lane == 0) redf[wv_] = bs;
  __syncthreads();
  if (tid == 0) {
    float tot = redf[0] + redf[1] + redf[2] + redf[3];
    int slot = (int)(blockIdx.x & (NSLOT - 1));
    float old = atomicAdd(&S_slot[16 * slot], tot);
    asm volatile("" : "+v"(old));   // consume: slot-add committed before cnt1
    int last = 0;
    unsigned t1 = atomicAdd(&cnt1[16 * slot], 1u);
    if (t1 == (unsigned)(BLK_PER_SLOT - 1)) {        // slot closed
      unsigned t2 = atomicAdd(cnt2, 1u);             // only 64 ever reach here
      last = (t2 == (unsigned)(NSLOT - 1)) ? 1 : 0;  // all slots closed
    }
    isLast = last;
  }
  __syncthreads();

  if (isLast) {
    float p  = ws[1024 + tid];
    float wd = ws[1280 + tid];
    float rp = wave_reduce_sum(p);
    float rw = wave_reduce_sum(wd);
    if (lane == 0) { redp[wv_] = rp; redw[wv_] = rw; }
    float sd = 0.0f;
    if (wv_ == 0) {
      float v = atomicAdd(&S_slot[16 * lane], 0.0f);  // coherent slot read
      sd = wave_reduce_sum(v);
    }
    __syncthreads();
    if (tid == 0) {
      float Sp   = redp[0] + redp[1] + redp[2] + redp[3];
      float Swpd = redw[0] + redw[1] + redw[2] + redw[3];
      float data_term = sd * (1.0f / ((float)B_N * (float)M_N));
      float wl = Swpd / (Sp + 1e-8f);
      float sparsity = Sp * (1.0f / ((float)M_N * (float)M_N));
      out[0] = data_term + LEN_C_ * wl + SP_C_ * sparsity;
    }
  }
}

extern "C" void kernel_launch(void* const* d_in, const int* in_sizes, int n_in,
                              void* d_out, int out_size, void* d_ws, size_t ws_size,
                              hipStream_t stream) {
  const float* data = (const float*)d_in[0];
  const float* w    = (const float*)d_in[1];
  const float* E    = (const float*)d_in[2];
  float* ws = (float*)d_ws;

  k_prep<<<2 * M_N, 256, 0, stream>>>(w, E, ws);
  k_main<<<GRID_MAIN, 256, 0, stream>>>(data, ws, (float*)d_out);
}

// Round 7
// 99.225 us; speedup vs baseline: 1.1181x; 1.0801x over previous
//
#include <hip/hip_runtime.h>
#include <math.h>

#define B_N 4096
#define M_N 256
#define D_N 256
#define ROWS 4                      // confirmed optimum: 2->43.4us, 4->41.5us, 8->47us
#define GRID_MAIN (B_N / ROWS)      // 1024
#define NSLOT 64                    // partial-sum slots (1 per 64B line)
#define BLK_PER_SLOT (GRID_MAIN / NSLOT)

constexpr float TAU_   = 0.2f;
constexpr float LAM_   = 8.0f;
constexpr float TOPO_  = 0.5f;
constexpr float LEN_C_ = 0.01f;
constexpr float SP_C_  = 0.001f;
constexpr float LOG2E_ = 1.44269504088896340736f;
constexpr float KSC    = LOG2E_ / TAU_;
constexpr float KL     = LOG2E_ / LAM_;
constexpr float C0_    = 133.0f;    // fixed exponent center: dist ~18.5 -> sc ~133

// ws float layout (R2 layout):
// [4]          cnt2 (uint, single)
// [16..272)    degree[256]
// [512..768)   wnorm[256]
// [1024..1280) pPart[256]
// [1280..1536) wpdPart[256]
// [2048..3072) S_slot[64] strided 16 floats (64B line each)
// [4096..5120) cnt1[64]  (uint) strided 16
// [8192..73728) wT[256*256]  (D x M transpose, fp32)

__device__ __forceinline__ float wave_reduce_sum(float v) {
#pragma unroll
  for (int off = 1; off < 64; off <<= 1) v += __shfl_xor(v, off, 64);
  return v;
}

// Quad-combine: sum of 4 sigmoids with ONE rcp (R1; kept).
__device__ __forceinline__ void rank_quad(float iv, float iv2, float4 q,
                                          float& s) {
  float ta = fmaf(q.x, iv, 1.0f);     // 1 + es_a*iv
  float da = fmaf(q.y, iv2, ta);      // D2a
  float na = ta + 1.0f;               // N2a
  float tb = fmaf(q.z, iv, 1.0f);
  float db = fmaf(q.w, iv2, tb);      // D2b
  float nb = tb + 1.0f;               // N2b
  float d4 = da * db;
  float n4 = fmaf(na, db, nb * da);
  s = fmaf(n4, __builtin_amdgcn_rcpf(d4), s);
}

// Dispatch 1 (R2 version, proven): blocks 0..255 transpose w -> wT + wnorm +
// zero accumulators; blocks 256..511 edge stats (reassociated, coalesced).
__global__ __launch_bounds__(256) void k_prep(const float* __restrict__ w,
                                              const float* __restrict__ E,
                                              float* __restrict__ ws) {
  int tid = threadIdx.x;
  if (blockIdx.x < M_N) {
    float* wT = ws + 8192;
    int j = blockIdx.x, d = tid;
    float v = w[j * D_N + d];
    wT[d * M_N + j] = v;
    float s = wave_reduce_sum(v * v);
    __shared__ float red[4];
    if ((d & 63) == 0) red[d >> 6] = s;
    if (j == 0) {
      if (d < 16) ws[d] = 0.0f;                       // cnt2 etc.
      if (d < NSLOT) {
        ws[2048 + 16 * d] = 0.0f;                     // S_slot
        ((unsigned*)ws)[4096 + 16 * d] = 0u;          // cnt1
      }
    }
    __syncthreads();
    if (d == 0) ws[512 + j] = red[0] + red[1] + red[2] + red[3];
  } else {
    int j = blockIdx.x - M_N;
    int k = tid;
    __shared__ __align__(16) float sp[M_N];   // p_k for this j
    __shared__ float redp[4], redt[4];

    float l = 0.5f * (E[j * M_N + k] + E[k * M_N + j]);
    float p = __builtin_amdgcn_rcpf(1.0f + __builtin_amdgcn_exp2f(-l * LOG2E_));
    if (k == j) p = 0.0f;
    sp[k] = p;

    float spw = wave_reduce_sum(p);
    if ((k & 63) == 0) redp[k >> 6] = spw;
    __syncthreads();
    float tp = redp[0] + redp[1] + redp[2] + redp[3];   // P (all threads)

    float A = 0.0f, Bv = 0.0f;
    const float4* sp4 = (const float4*)sp;
    const float* wb = w + tid;
#pragma unroll 4
    for (int k0 = 0; k0 < M_N / 4; k0++) {
      float4 pq = sp4[k0];
      const float* wr = wb + (size_t)(4 * k0) * D_N;
      float w0 = wr[0], w1 = wr[D_N], w2 = wr[2 * D_N], w3 = wr[3 * D_N];
      A  = fmaf(pq.x, w0 * w0, A); Bv = fmaf(pq.x, w0, Bv);
      A  = fmaf(pq.y, w1 * w1, A); Bv = fmaf(pq.y, w1, Bv);
      A  = fmaf(pq.z, w2 * w2, A); Bv = fmaf(pq.z, w2, Bv);
      A  = fmaf(pq.w, w3 * w3, A); Bv = fmaf(pq.w, w3, Bv);
    }

    float wj = w[j * D_N + tid];
    float v  = fmaf(tp, wj * wj, fmaf(-2.0f * wj, Bv, A));
    float sv = wave_reduce_sum(v);
    if ((k & 63) == 0) redt[k >> 6] = sv;
    __syncthreads();
    if (k == 0) {
      float tw = redt[0] + redt[1] + redt[2] + redt[3];
      ws[16 + j]   = tp * (1.0f / (float)(M_N - 1));
      ws[1024 + j] = tp;
      ws[1280 + j] = tw;
    }
  }
}

// Dispatch 2: fused fp32 GEMM + soft-rank. ROWS=4 (scanned optimum) with
// R6's instruction cuts kept: wave-owned row norms (wave v owns row v,
// one float4/lane, -1 barrier) and shfl-built ewp pairs (ew[] array,
// its LDS round-trip, the hoist pass and -1 more barrier all deleted).
__global__ __launch_bounds__(256, 4) void k_main(const float* __restrict__ data,
                                                 float* __restrict__ ws,
                                                 float* __restrict__ out) {
  const float* wT     = ws + 8192;
  const float* wnorm  = ws + 512;
  const float* degree = ws + 16;
  float* S_slot  = ws + 2048;                 // stride 16 floats
  unsigned* cnt1 = (unsigned*)ws + 4096;      // stride 16
  unsigned* cnt2 = (unsigned*)ws + 4;

  __shared__ __align__(16) float ewp[ROWS][M_N];  // pairs: [2p]=es, [2p+1]=ep
  __shared__ float snrm[ROWS];
  __shared__ float redf[4], redp[4], redw[4];
  __shared__ int isLast;

  const int tid  = threadIdx.x;
  const int wv_  = tid >> 6;
  const int lane = tid & 63;
  const int b0   = blockIdx.x * ROWS;

  // row norms: wave v owns row v; one float4 per lane (64*16B = full row)
  {
    float4 xv = ((const float4*)(data + (size_t)(b0 + wv_) * D_N))[lane];
    float s = wave_reduce_sum(fmaf(xv.x, xv.x, fmaf(xv.y, xv.y,
                              fmaf(xv.z, xv.z, xv.w * xv.w))));
    if (lane == 0) snrm[wv_] = s;
  }
  // (snrm consumed after the GEMM barrier below — no extra barrier needed)

  // GEMM: x rows block-uniform (s_load float4); wT coalesced per thread.
  // Register double-buffer: batch g+1's 16 loads issued before batch g is
  // consumed -> 16+ loads in flight at consumption.
  const float4* x0 = (const float4*)(data + (size_t)(b0 + 0) * D_N);
  const float4* x1 = (const float4*)(data + (size_t)(b0 + 1) * D_N);
  const float4* x2 = (const float4*)(data + (size_t)(b0 + 2) * D_N);
  const float4* x3 = (const float4*)(data + (size_t)(b0 + 3) * D_N);
  const float* pw = wT + tid;

  float a0 = 0.f, a1 = 0.f, a2 = 0.f, a3 = 0.f;
  float wreg[2][16];
#pragma unroll
  for (int i = 0; i < 16; i++) wreg[0][i] = pw[(size_t)i * M_N];

#pragma unroll
  for (int g = 0; g < 16; g++) {
    const int cur = g & 1, nxt = cur ^ 1;
    if (g < 15) {
#pragma unroll
      for (int i = 0; i < 16; i++)
        wreg[nxt][i] = pw[(size_t)((g + 1) * 16 + i) * M_N];
    }
#pragma unroll
    for (int i4 = 0; i4 < 4; i4++) {
      int d4 = 4 * g + i4;
      float4 xa = x0[d4], xb = x1[d4], xc = x2[d4], xd = x3[d4];
      float w0 = wreg[cur][4 * i4 + 0], w1 = wreg[cur][4 * i4 + 1];
      float w2 = wreg[cur][4 * i4 + 2], w3 = wreg[cur][4 * i4 + 3];
      a0 = fmaf(xa.x, w0, a0); a0 = fmaf(xa.y, w1, a0);
      a0 = fmaf(xa.z, w2, a0); a0 = fmaf(xa.w, w3, a0);
      a1 = fmaf(xb.x, w0, a1); a1 = fmaf(xb.y, w1, a1);
      a1 = fmaf(xb.z, w2, a1); a1 = fmaf(xb.w, w3, a1);
      a2 = fmaf(xc.x, w0, a2); a2 = fmaf(xc.y, w1, a2);
      a2 = fmaf(xc.z, w2, a2); a2 = fmaf(xc.w, w3, a2);
      a3 = fmaf(xd.x, w0, a3); a3 = fmaf(xd.y, w1, a3);
      a3 = fmaf(xd.z, w2, a3); a3 = fmaf(xd.w, w3, a3);
    }
  }
  __syncthreads();   // snrm visible; GEMM regs done

  // distances + e-values; ewp pairs built in-register via partner shuffle
  float wn = wnorm[tid];
  float acc[ROWS] = {a0, a1, a2, a3};
  float dist[ROWS], iv[ROWS], iv2[ROWS];
#pragma unroll
  for (int r = 0; r < ROWS; r++) {
    float sq = snrm[r] - 2.0f * acc[r] + wn;
    dist[r] = sqrtf(fmaxf(sq, 0.0f));
    float sc = dist[r] * KSC;
    float ev = __builtin_amdgcn_exp2f(sc - C0_);
    iv[r]    = __builtin_amdgcn_exp2f(C0_ - sc);
    iv2[r]   = iv[r] * iv[r];
    float en = __shfl_xor(ev, 1, 64);          // partner j = tid^1
    if ((tid & 1) == 0) {                      // even lane owns pair idx tid/2
      float2 o = {ev + en, ev * en};
      *(float2*)&ewp[r][tid] = o;              // elements [tid], [tid+1]
    }
  }
  __syncthreads();

  // rank: per row, sum_k sigmoid((d_j-d_k)/tau), quad-combined (1 rcp / 4k)
  float fj = 1.0f + TOPO_ * degree[tid];
  float tl = 0.0f;
#pragma unroll
  for (int r = 0; r < ROWS; r++) {
    float s = 0.0f;
    const float4* q4 = (const float4*)(&ewp[r][0]);
    float ivr = iv[r], iv2r = iv2[r];
#pragma unroll 8
    for (int k4 = 0; k4 < M_N / 4; k4++) {
      float4 q = q4[k4];                       // (es_a, ep_a, es_b, ep_b)
      rank_quad(ivr, iv2r, q, s);
    }
    // diagonal contributes exactly 0.5; soft_rank-1 = s-0.5
    float nb = __builtin_amdgcn_exp2f((0.5f - s) * KL);
    tl = fmaf(nb * dist[r], fj, tl);
  }

  float bs = wave_reduce_sum(tl);
  if (lane == 0) redf[wv_] = bs;
  __syncthreads();
  if (tid == 0) {
    float tot = redf[0] + redf[1] + redf[2] + redf[3];
    int slot = (int)(blockIdx.x & (NSLOT - 1));
    float old = atomicAdd(&S_slot[16 * slot], tot);
    asm volatile("" : "+v"(old));   // consume: slot-add committed before cnt1
    int last = 0;
    unsigned t1 = atomicAdd(&cnt1[16 * slot], 1u);
    if (t1 == (unsigned)(BLK_PER_SLOT - 1)) {        // slot closed
      unsigned t2 = atomicAdd(cnt2, 1u);             // only 64 ever reach here
      last = (t2 == (unsigned)(NSLOT - 1)) ? 1 : 0;  // all slots closed
    }
    isLast = last;
  }
  __syncthreads();

  if (isLast) {
    float p  = ws[1024 + tid];
    float wd = ws[1280 + tid];
    float rp = wave_reduce_sum(p);
    float rw = wave_reduce_sum(wd);
    if (lane == 0) { redp[wv_] = rp; redw[wv_] = rw; }
    float sd = 0.0f;
    if (wv_ == 0) {
      float v = atomicAdd(&S_slot[16 * lane], 0.0f);  // coherent slot read
      sd = wave_reduce_sum(v);
    }
    __syncthreads();
    if (tid == 0) {
      float Sp   = redp[0] + redp[1] + redp[2] + redp[3];
      float Swpd = redw[0] + redw[1] + redw[2] + redw[3];
      float data_term = sd * (1.0f / ((float)B_N * (float)M_N));
      float wl = Swpd / (Sp + 1e-8f);
      float sparsity = Sp * (1.0f / ((float)M_N * (float)M_N));
      out[0] = data_term + LEN_C_ * wl + SP_C_ * sparsity;
    }
  }
}

extern "C" void kernel_launch(void* const* d_in, const int* in_sizes, int n_in,
                              void* d_out, int out_size, void* d_ws, size_t ws_size,
                              hipStream_t stream) {
  const float* data = (const float*)d_in[0];
  const float* w    = (const float*)d_in[1];
  const float* E    = (const float*)d_in[2];
  float* ws = (float*)d_ws;

  k_prep<<<2 * M_N, 256, 0, stream>>>(w, E, ws);
  k_main<<<GRID_MAIN, 256, 0, stream>>>(data, ws, (float*)d_out);
}